// Round 12
// baseline (189.048 us; speedup 1.0000x reference)
//
#include <hip/hip_runtime.h>
#include <hip/hip_bf16.h>
#include <cstdint>
#include <cstddef>

#define BATCH   8192
#define NSAMP   8192
#define DIM     512
#define NCLASS  50000
#define HBINS   50176    // 256 blocks * 196 bins >= NCLASS

typedef __attribute__((ext_vector_type(8))) short bf16x8;
typedef __attribute__((ext_vector_type(4))) float f32x4;

// -log(expected_count(c)) for the log-uniform sampler, in double to match the
// numpy reference (f32 log(c+2)-log(c+1) catastrophically cancels at large c).
__device__ __forceinline__ float neg_log_expected(int c) {
    double p = log1p(1.0 / (double)(c + 1)) / log((double)(NCLASS + 1));
    double e = -expm1((double)NSAMP * log1p(-p));
    return (float)(-log(e));
}

__device__ __forceinline__ unsigned short f2bf(float f) {
    __hip_bfloat16 h = __float2bfloat16(f);
    return *reinterpret_cast<unsigned short*>(&h);
}

__device__ __forceinline__ void gload_lds16(const void* g, void* l) {
    __builtin_amdgcn_global_load_lds(
        (const __attribute__((address_space(1))) void*)g,
        (__attribute__((address_space(3))) void*)l, 16, 0, 0);
}

// ==== dedupe pipeline (deterministic: scan-based) ===========================
__global__ void k_hist(const int* __restrict__ sampled, int* __restrict__ hist) {
    atomicAdd(&hist[sampled[blockIdx.x * 1024 + threadIdx.x]], 1);
}
// per-block distinct counts (256 blocks x 196 bins)
__global__ void k_scan1(const int* __restrict__ hist, int* __restrict__ btot) {
    int b = blockIdx.x, t = threadIdx.x;
    int c = b * 196 + t;
    int x = (t < 196 && c < NCLASS && hist[c] > 0) ? 1 : 0;
    int lane = t & 63, wv = t >> 6;
    #pragma unroll
    for (int off = 32; off; off >>= 1) x += __shfl_down(x, off, 64);
    __shared__ int ws[4];
    if (lane == 0) ws[wv] = x;
    __syncthreads();
    if (t == 0) btot[b] = ws[0] + ws[1] + ws[2] + ws[3];
}
// exclusive scan of the 256 block totals; meta = {D, padD}
__global__ void k_scan2(const int* __restrict__ btot, int* __restrict__ boff,
                        int* __restrict__ meta) {
    int t = threadIdx.x;
    int v = btot[t];
    int lane = t & 63, wv = t >> 6;
    int x = v;
    #pragma unroll
    for (int off = 1; off < 64; off <<= 1) {
        int y = __shfl_up(x, off, 64);
        if (lane >= off) x += y;
    }
    __shared__ int ws[4];
    if (lane == 63) ws[wv] = x;
    __syncthreads();
    int base = 0;
    for (int w = 0; w < wv; ++w) base += ws[w];
    boff[t] = base + x - v;
    if (t == 255) {
        int D = base + x;
        meta[0] = D;
        meta[1] = (D + 127) & ~127;
    }
}
// scatter distinct class ids to compact positions (deterministic)
__global__ void k_scatter(const int* __restrict__ hist, const int* __restrict__ boff,
                          int* __restrict__ didx) {
    int b = blockIdx.x, t = threadIdx.x;
    int c = b * 196 + t;
    int ind = (t < 196 && c < NCLASS && hist[c] > 0) ? 1 : 0;
    int lane = t & 63, wv = t >> 6;
    int x = ind;
    #pragma unroll
    for (int off = 1; off < 64; off <<= 1) {
        int y = __shfl_up(x, off, 64);
        if (lane >= off) x += y;
    }
    __shared__ int ws[4];
    if (lane == 63) ws[wv] = x;
    __syncthreads();
    int base = boff[b];
    for (int w = 0; w < wv; ++w) base += ws[w];
    if (ind) didx[base + x - 1] = c;
}

// ==== prep (256 thr, 2 rows/block) ==========================================
// blocks [0,4096): inputs f32->bf16; true logit; row_sum seed = (1-m)*exp(tl)
// blocks [4096,8192): s<D: gather W[didx[s]]->bf16, adj=bias+nle+ln(m);
//                     D<=s<padD: zero row, adj=-1e5
__global__ __launch_bounds__(256) void k_prep(
    const float* __restrict__ inputs, const int* __restrict__ labels,
    const float* __restrict__ W, const float* __restrict__ bias,
    const int* __restrict__ hist, const int* __restrict__ didx,
    const int* __restrict__ meta,
    __hip_bfloat16* __restrict__ Abf, __hip_bfloat16* __restrict__ Bbf,
    float* __restrict__ adj,
    float* __restrict__ true_logit, float* __restrict__ row_sum) {
    int bid = blockIdx.x;
    int t   = threadIdx.x;
    int rh  = t >> 7;                            // row half: 0/1
    int t1  = t & 127;
    if (bid < BATCH / 2) {
        int row = bid * 2 + rh;
        float4 v = reinterpret_cast<const float4*>(inputs + (size_t)row * DIM)[t1];
        ushort4 u;
        u.x = f2bf(v.x); u.y = f2bf(v.y); u.z = f2bf(v.z); u.w = f2bf(v.w);
        reinterpret_cast<ushort4*>(Abf + (size_t)row * DIM)[t1] = u;

        int lbl = labels[row];
        float4 w = reinterpret_cast<const float4*>(W + (size_t)lbl * DIM)[t1];
        float dot = v.x * w.x + v.y * w.y + v.z * w.z + v.w * w.w;
        #pragma unroll
        for (int off = 32; off; off >>= 1) dot += __shfl_down(dot, off, 64);
        __shared__ float red[4];
        if ((t & 63) == 0) red[t >> 6] = dot;
        __syncthreads();
        if (t1 == 0) {
            float tl = red[rh * 2] + red[rh * 2 + 1] + bias[lbl] + neg_log_expected(lbl);
            true_logit[row] = tl;
            row_sum[row]    = (1.0f - (float)hist[lbl]) * __expf(tl);
        }
    } else {
        int s = (bid - BATCH / 2) * 2 + rh;
        int D = meta[0], padD = meta[1];
        if (s >= padD) return;
        if (s < D) {
            int idx = didx[s];
            float4 v = reinterpret_cast<const float4*>(W + (size_t)idx * DIM)[t1];
            ushort4 u;
            u.x = f2bf(v.x); u.y = f2bf(v.y); u.z = f2bf(v.z); u.w = f2bf(v.w);
            reinterpret_cast<ushort4*>(Bbf + (size_t)s * DIM)[t1] = u;
            if (t1 == 0)
                adj[s] = bias[idx] + neg_log_expected(idx) + logf((float)hist[idx]);
        } else {
            ushort4 z; z.x = z.y = z.z = z.w = 0;
            reinterpret_cast<ushort4*>(Bbf + (size_t)s * DIM)[t1] = z;
            if (t1 == 0) adj[s] = -100000.0f;
        }
    }
}

// ==== GEMM (round-10 structure, unchanged) + fused final ====================
// 128x128 tile, BK=32, 4 waves (2x2), 2-buf stage->read->MFMA->__syncthreads,
// 4 resident blocks/CU, involutive granule swizzle (0 conflicts), XCD raster,
// col-tiles strided by 16 across cgrps. After a block's last epilogue it
// increments cnt[rb] (threadfence-ordered); the 16th block of a row band
// computes loss = log(row_sum) - true_logit for the band (row_sum read via
// atomicAdd(p,0.0f): L2-coherent, no stale-L1 risk; bands are XCD-local).
__global__ __launch_bounds__(256, 4) void k_gemm(
    const __hip_bfloat16* __restrict__ A, const __hip_bfloat16* __restrict__ B,
    const float* __restrict__ adj, const int* __restrict__ meta,
    float* __restrict__ row_sum, const float* __restrict__ true_logit,
    float* __restrict__ loss, int* __restrict__ cnt) {
    __shared__ alignas(16) __hip_bfloat16 Asm[2][128 * 32];   // 16 KiB
    __shared__ alignas(16) __hip_bfloat16 Bsm[2][128 * 32];   // 16 KiB
    __shared__ float tsum[2][128];                            // 1 KiB

    const int tid  = threadIdx.x;
    const int wave = tid >> 6;
    const int lane = tid & 63;
    const int wr   = wave >> 1;
    const int wc   = wave & 1;

    const int bid  = blockIdx.x;
    const int xcd  = bid & 7;
    const int u    = bid >> 3;
    const int rb   = xcd * 8 + (u & 7);
    const int cgrp = u >> 3;                   // 0..15
    const int brow = rb * 128;

    const int nct = meta[1] >> 7;              // padD / 128 col-tiles
    const int ntl = (nct > cgrp) ? (((nct - cgrp - 1) >> 4) + 1) : 0;
    const int nsteps = ntl << 4;

    const int srow = lane >> 2;
    const int sg   = (lane & 3) ^ ((lane >> 3) & 3);
    const int rsel = lane & 15;
    const int koff = ((lane >> 4) ^ ((lane >> 1) & 3)) * 8;

    if (nsteps > 0) {
        f32x4 acc[4][4];
        #pragma unroll
        for (int m = 0; m < 4; ++m)
            #pragma unroll
            for (int n = 0; n < 4; ++n)
                acc[m][n] = (f32x4){0.f, 0.f, 0.f, 0.f};

        auto stage = [&](int g) {
            const int buf = g & 1, t = g >> 4, kt = g & 15;
            const int bcol = (cgrp + t * 16) << 7;
            #pragma unroll
            for (int i = 0; i < 2; ++i) {
                const __hip_bfloat16* gA =
                    A + (size_t)(brow + wave * 32 + i * 16 + srow) * DIM + kt * 32 + sg * 8;
                gload_lds16(gA, &Asm[buf][(wave * 32 + i * 16) * 32]);
                const __hip_bfloat16* gB =
                    B + (size_t)(bcol + wave * 32 + i * 16 + srow) * DIM + kt * 32 + sg * 8;
                gload_lds16(gB, &Bsm[buf][(wave * 32 + i * 16) * 32]);
            }
        };

        auto body = [&](int buf) {
            bf16x8 a[4], b[4];
            #pragma unroll
            for (int m = 0; m < 4; ++m)
                a[m] = *reinterpret_cast<const bf16x8*>(
                    &Asm[buf][(wr * 64 + m * 16 + rsel) * 32 + koff]);
            #pragma unroll
            for (int n = 0; n < 4; ++n)
                b[n] = *reinterpret_cast<const bf16x8*>(
                    &Bsm[buf][(wc * 64 + n * 16 + rsel) * 32 + koff]);
            #pragma unroll
            for (int m = 0; m < 4; ++m)
                #pragma unroll
                for (int n = 0; n < 4; ++n)
                    acc[m][n] = __builtin_amdgcn_mfma_f32_16x16x32_bf16(a[m], b[n], acc[m][n], 0, 0, 0);
        };

        auto epi = [&](int i) {
            const int bcol = (cgrp + i * 16) << 7;
            float aadj[4];
            #pragma unroll
            for (int n = 0; n < 4; ++n) aadj[n] = adj[bcol + wc * 64 + n * 16 + rsel];
            #pragma unroll
            for (int m = 0; m < 4; ++m) {
                #pragma unroll
                for (int r = 0; r < 4; ++r) {
                    int lr = wr * 64 + m * 16 + (lane >> 4) * 4 + r;
                    float part = 0.f;
                    #pragma unroll
                    for (int n = 0; n < 4; ++n)
                        part += __expf(acc[m][n][r] + aadj[n]);
                    part += __shfl_xor(part, 1, 16);
                    part += __shfl_xor(part, 2, 16);
                    part += __shfl_xor(part, 4, 16);
                    part += __shfl_xor(part, 8, 16);
                    if (rsel == 0) tsum[wc][lr] = part;
                }
            }
            __syncthreads();
            if (tid < 128)
                atomicAdd(&row_sum[brow + tid], tsum[0][tid] + tsum[1][tid]);
            #pragma unroll
            for (int m = 0; m < 4; ++m)
                #pragma unroll
                for (int n = 0; n < 4; ++n)
                    acc[m][n] = (f32x4){0.f, 0.f, 0.f, 0.f};
        };

        stage(0);
        __syncthreads();

        #pragma unroll 1
        for (int g = 0; g < nsteps; ++g) {
            if (g + 1 < nsteps) stage(g + 1);
            body(g & 1);
            if ((g & 15) == 15) epi(g >> 4);
            __syncthreads();
        }
    }

    // fused final: last block of this row band computes the loss
    __threadfence();
    __shared__ int done;
    if (tid == 0) done = atomicAdd(&cnt[rb], 1);
    __syncthreads();
    if (done == 15 && tid < 128) {
        int r = brow + tid;
        float rs = atomicAdd(&row_sum[r], 0.0f);   // coherent read
        loss[r] = logf(rs) - true_logit[r];
    }
}

extern "C" void kernel_launch(void* const* d_in, const int* in_sizes, int n_in,
                              void* d_out, int out_size, void* d_ws, size_t ws_size,
                              hipStream_t stream) {
    const float* inputs  = (const float*)d_in[0];
    const int*   labels  = (const int*)d_in[1];
    const float* W       = (const float*)d_in[2];
    const float* bias    = (const float*)d_in[3];
    const int*   sampled = (const int*)d_in[4];
    float*       loss    = (float*)d_out;

    char* ws = (char*)d_ws;
    __hip_bfloat16* Abf = (__hip_bfloat16*)ws;                                  // 8 MiB
    __hip_bfloat16* Bbf = (__hip_bfloat16*)(ws + (size_t)BATCH * DIM * 2);      // 8 MiB
    size_t off = (size_t)(BATCH + NSAMP) * DIM * 2;
    float* adj        = (float*)(ws + off);            off += NSAMP * 4;
    float* true_logit = (float*)(ws + off);            off += BATCH * 4;
    float* row_sum    = (float*)(ws + off);            off += BATCH * 4;
    int*   hist       = (int*)(ws + off);              off += HBINS * 4;
    int*   cnt        = (int*)(ws + off);              off += 64 * 4;           // after hist: one memset
    int*   btot       = (int*)(ws + off);              off += 256 * 4;
    int*   boff       = (int*)(ws + off);              off += 256 * 4;
    int*   meta       = (int*)(ws + off);              off += 16;
    int*   didx       = (int*)(ws + off);              off += NSAMP * 4;

    hipMemsetAsync(hist, 0, (size_t)HBINS * 4 + 64 * 4, stream);   // hist + cnt
    hipLaunchKernelGGL(k_hist,    dim3(NSAMP / 1024), dim3(1024), 0, stream, sampled, hist);
    hipLaunchKernelGGL(k_scan1,   dim3(256), dim3(256), 0, stream, hist, btot);
    hipLaunchKernelGGL(k_scan2,   dim3(1),   dim3(256), 0, stream, btot, boff, meta);
    hipLaunchKernelGGL(k_scatter, dim3(256), dim3(256), 0, stream, hist, boff, didx);
    hipLaunchKernelGGL(k_prep,    dim3(BATCH), dim3(256), 0, stream,
                       inputs, labels, W, bias, hist, didx, meta,
                       Abf, Bbf, adj, true_logit, row_sum);
    hipLaunchKernelGGL(k_gemm,    dim3(1024), dim3(256), 0, stream,
                       Abf, Bbf, adj, meta, row_sum, true_logit, loss, cnt);
}